// Round 6
// baseline (547.968 us; speedup 1.0000x reference)
//
#include <hip/hip_runtime.h>

#define N_NODES 100000
#define N_EDGES 1600000
#define IN_C 256
#define HID 128
#define NEG_SLOPE 0.2f
#define BN_EPS 1e-5f
#define NBUCK 391          // ceil(N_NODES/256): bucket b covers dst [b*256,(b+1)*256)
#define NPART 391          // ceil(N_EDGES/4096) partition tiles

typedef unsigned int uint32;
typedef __attribute__((ext_vector_type(8))) short bf16x8;
typedef __attribute__((ext_vector_type(4))) float f32x4;

__device__ __forceinline__ float lrelu(float x) { return x > 0.f ? x : NEG_SLOPE * x; }

__device__ __forceinline__ unsigned short f2bf(float f) {
    uint32 u = __float_as_uint(f);
    u += 0x7fffu + ((u >> 16) & 1u);
    return (unsigned short)(u >> 16);
}
__device__ __forceinline__ float bf2f(unsigned short h) {
    return __uint_as_float(((uint32)h) << 16);
}
__device__ __forceinline__ float bflo(uint32 v) { return __uint_as_float(v << 16); }
__device__ __forceinline__ float bfhi(uint32 v) { return __uint_as_float(v & 0xffff0000u); }
__device__ __forceinline__ uint32 packbf(float a, float b) {
    return (uint32)f2bf(a) | ((uint32)f2bf(b) << 16);
}

// ---------------- init ----------------
__global__ void k_init(int* __restrict__ bcount, float* __restrict__ bnacc) {
    int t = threadIdx.x;
    if (t < NBUCK) bcount[t] = 0;
    if (t < 512) bnacc[t] = 0.f;
}

// ---------------- transpose both W: [K][128] fp32 -> [128][K] bf16 ----------------
__global__ void k_transpose_all(const float* __restrict__ W1, const float* __restrict__ W2,
                                unsigned short* __restrict__ Wt1,
                                unsigned short* __restrict__ Wt2) {
    int idx = blockIdx.x * 256 + threadIdx.x;
    if (idx < IN_C * 128) {
        int k = idx >> 7, n = idx & 127;
        Wt1[n * IN_C + k] = f2bf(W1[idx]);
    } else {
        idx -= IN_C * 128;
        if (idx < HID * 128) {
            int k = idx >> 7, n = idx & 127;
            Wt2[n * HID + k] = f2bf(W2[idx]);
        }
    }
}

// ---------------- MFMA GEMM, register-prefetch pipelined ----------------
template <bool AF32, bool OUTF32>
__global__ __launch_bounds__(256) void k_gemm(const void* __restrict__ Av,
                                              const unsigned short* __restrict__ Wt,
                                              void* __restrict__ Out, int K) {
    __shared__ unsigned short As[128 * 72];
    __shared__ unsigned short Bs[128 * 72];
    const int t = threadIdx.x;
    const int n0 = blockIdx.x * 128;
    const int wv = t >> 6, lane = t & 63;
    const int wy = wv >> 1, wx = wv & 1;
    const int lm = lane & 15, lg = lane >> 4;
    const float* Af = (const float*)Av;
    const unsigned short* Ah = (const unsigned short*)Av;

    f32x4 acc[4][4];
#pragma unroll
    for (int i = 0; i < 4; ++i)
#pragma unroll
        for (int j = 0; j < 4; ++j) acc[i][j] = (f32x4){0.f, 0.f, 0.f, 0.f};

    float4 afp[8];
    uint4 ahp[4];
    uint4 bvp[4];

    if (AF32) {
#pragma unroll
        for (int p = 0; p < 8; ++p) {
            int idx = p * 256 + t, row = idx >> 4, c4 = idx & 15, gn = n0 + row;
            afp[p] = (gn < N_NODES) ? *(const float4*)&Af[(size_t)gn * K + c4 * 4]
                                    : make_float4(0.f, 0.f, 0.f, 0.f);
        }
    } else {
#pragma unroll
        for (int p = 0; p < 4; ++p) {
            int idx = p * 256 + t, row = idx >> 3, c = idx & 7, gn = n0 + row;
            ahp[p] = (gn < N_NODES) ? *(const uint4*)&Ah[(size_t)gn * K + c * 8]
                                    : make_uint4(0, 0, 0, 0);
        }
    }
#pragma unroll
    for (int p = 0; p < 4; ++p) {
        int idx = p * 256 + t, n = idx >> 3, c = idx & 7;
        bvp[p] = *(const uint4*)&Wt[(size_t)n * K + c * 8];
    }

    for (int kc = 0; kc < K; kc += 64) {
        if (AF32) {
#pragma unroll
            for (int p = 0; p < 8; ++p) {
                int idx = p * 256 + t, row = idx >> 4, c4 = idx & 15;
                ushort4 b;
                b.x = f2bf(afp[p].x); b.y = f2bf(afp[p].y);
                b.z = f2bf(afp[p].z); b.w = f2bf(afp[p].w);
                *(ushort4*)&As[row * 72 + c4 * 4] = b;
            }
        } else {
#pragma unroll
            for (int p = 0; p < 4; ++p) {
                int idx = p * 256 + t, row = idx >> 3, c = idx & 7;
                *(uint4*)&As[row * 72 + c * 8] = ahp[p];
            }
        }
#pragma unroll
        for (int p = 0; p < 4; ++p) {
            int idx = p * 256 + t, n = idx >> 3, c = idx & 7;
            *(uint4*)&Bs[n * 72 + c * 8] = bvp[p];
        }
        __syncthreads();
        int kn = kc + 64;
        if (kn < K) {
            if (AF32) {
#pragma unroll
                for (int p = 0; p < 8; ++p) {
                    int idx = p * 256 + t, row = idx >> 4, c4 = idx & 15, gn = n0 + row;
                    afp[p] = (gn < N_NODES) ? *(const float4*)&Af[(size_t)gn * K + kn + c4 * 4]
                                            : make_float4(0.f, 0.f, 0.f, 0.f);
                }
            } else {
#pragma unroll
                for (int p = 0; p < 4; ++p) {
                    int idx = p * 256 + t, row = idx >> 3, c = idx & 7, gn = n0 + row;
                    ahp[p] = (gn < N_NODES) ? *(const uint4*)&Ah[(size_t)gn * K + kn + c * 8]
                                            : make_uint4(0, 0, 0, 0);
                }
            }
#pragma unroll
            for (int p = 0; p < 4; ++p) {
                int idx = p * 256 + t, n = idx >> 3, c = idx & 7;
                bvp[p] = *(const uint4*)&Wt[(size_t)n * K + kn + c * 8];
            }
        }
#pragma unroll
        for (int ks = 0; ks < 2; ++ks) {
            bf16x8 af[4], bfr[4];
#pragma unroll
            for (int i = 0; i < 4; ++i)
                af[i] = *(const bf16x8*)&As[(wy * 64 + i * 16 + lm) * 72 + ks * 32 + lg * 8];
#pragma unroll
            for (int j = 0; j < 4; ++j)
                bfr[j] = *(const bf16x8*)&Bs[(wx * 64 + j * 16 + lm) * 72 + ks * 32 + lg * 8];
#pragma unroll
            for (int i = 0; i < 4; ++i)
#pragma unroll
                for (int j = 0; j < 4; ++j)
                    acc[i][j] = __builtin_amdgcn_mfma_f32_16x16x32_bf16(af[i], bfr[j],
                                                                        acc[i][j], 0, 0, 0);
        }
        __syncthreads();
    }
#pragma unroll
    for (int i = 0; i < 4; ++i) {
#pragma unroll
        for (int r = 0; r < 4; ++r) {
            int row = n0 + wy * 64 + i * 16 + lg * 4 + r;
            if (row < N_NODES) {
#pragma unroll
                for (int j = 0; j < 4; ++j) {
                    int col = wx * 64 + j * 16 + lm;
                    float v = acc[i][j][r];
                    if (OUTF32) ((float*)Out)[(size_t)row * 128 + col] = v;
                    else ((unsigned short*)Out)[(size_t)row * 128 + col] = f2bf(v);
                }
            }
        }
    }
}

// ---------------- attention coefficients ----------------
__global__ __launch_bounds__(256) void k_att(const unsigned short* __restrict__ hb,
                                             const float* __restrict__ att_s,
                                             const float* __restrict__ att_d,
                                             float* __restrict__ a_src,
                                             float* __restrict__ a_dst) {
    int node = blockIdx.x * 2 + (threadIdx.x >> 7);
    int c = threadIdx.x & 127;
    float hv = bf2f(hb[(size_t)node * 128 + c]);
    float ps = hv * att_s[c];
    float pd = hv * att_d[c];
#pragma unroll
    for (int m = 1; m < 32; m <<= 1) {
        ps += __shfl_xor(ps, m);
        pd += __shfl_xor(pd, m);
    }
    if ((c & 31) == 0) {
        int head = c >> 5;
        a_src[node * 4 + head] = ps;
        a_dst[node * 4 + head] = pd;
    }
}

// ---------------- CSR build: two-phase bucket sort ----------------
__global__ __launch_bounds__(256) void k_bucket_count(const int* __restrict__ ei,
                                                      int* __restrict__ bcount) {
    __shared__ int hist[NBUCK];
    for (int i = threadIdx.x; i < NBUCK; i += 256) hist[i] = 0;
    __syncthreads();
    for (int e = blockIdx.x * 256 + threadIdx.x; e < N_EDGES; e += gridDim.x * 256)
        atomicAdd(&hist[ei[N_EDGES + e] >> 8], 1);
    __syncthreads();
    for (int i = threadIdx.x; i < NBUCK; i += 256)
        if (hist[i]) atomicAdd(&bcount[i], hist[i]);
}

__global__ void k_bucket_scan(const int* __restrict__ bcount, int* __restrict__ bucket_base,
                              int* __restrict__ gcursor, int* __restrict__ row_ptr) {
    __shared__ int sh[512];
    int t = threadIdx.x;
    int v0 = (t < NBUCK) ? bcount[t] : 0;
    int val = v0;
    sh[t] = val;
    __syncthreads();
    for (int off = 1; off < 512; off <<= 1) {
        int o = (t >= off) ? sh[t - off] : 0;
        __syncthreads();
        val += o;
        sh[t] = val;
        __syncthreads();
    }
    if (t < NBUCK) {
        int e = val - v0;
        bucket_base[t] = e;
        gcursor[t] = e;
    }
    if (t == 0) {
        bucket_base[NBUCK] = N_EDGES;
        row_ptr[N_NODES] = N_EDGES;
    }
}

__global__ __launch_bounds__(256) void k_partition(const int* __restrict__ ei,
                                                   int* __restrict__ gcursor,
                                                   int* __restrict__ staging) {
    __shared__ int hist[NBUCK];
    __shared__ int base[NBUCK];
    int t = threadIdx.x;
    int e0 = blockIdx.x * 4096;
    for (int i = t; i < NBUCK; i += 256) hist[i] = 0;
    __syncthreads();
    int pk[16], cb[16];
#pragma unroll
    for (int u = 0; u < 16; ++u) {
        int e = e0 + u * 256 + t;
        cb[u] = -1;
        if (e < N_EDGES) {
            int s = ei[e], d = ei[N_EDGES + e];
            int b = d >> 8;
            int r = atomicAdd(&hist[b], 1);
            pk[u] = ((d & 255) << 17) | s;
            cb[u] = (r << 9) | b;
        }
    }
    __syncthreads();
    for (int i = t; i < NBUCK; i += 256)
        if (hist[i]) base[i] = atomicAdd(&gcursor[i], hist[i]);
    __syncthreads();
#pragma unroll
    for (int u = 0; u < 16; ++u) {
        if (cb[u] >= 0) {
            int b = cb[u] & 511, r = cb[u] >> 9;
            staging[base[b] + r] = pk[u];
        }
    }
}

__global__ __launch_bounds__(256) void k_bucket_sort(const int* __restrict__ staging,
                                                     const int* __restrict__ bucket_base,
                                                     int* __restrict__ row_ptr,
                                                     int* __restrict__ sorted_src) {
    __shared__ int hist[256];
    __shared__ int sh[256];
    int t = threadIdx.x, b = blockIdx.x;
    int lo = bucket_base[b], hi = bucket_base[b + 1];
    hist[t] = 0;
    __syncthreads();
    for (int i = lo + t; i < hi; i += 256) atomicAdd(&hist[staging[i] >> 17], 1);
    __syncthreads();
    int v0 = hist[t];
    int val = v0;
    sh[t] = val;
    __syncthreads();
    for (int off = 1; off < 256; off <<= 1) {
        int o = (t >= off) ? sh[t - off] : 0;
        __syncthreads();
        val += o;
        sh[t] = val;
        __syncthreads();
    }
    int excl = val - v0;
    int d = b * 256 + t;
    if (d < N_NODES) row_ptr[d] = lo + excl;
    hist[t] = excl;
    __syncthreads();
    for (int i = lo + t; i < hi; i += 256) {
        int p = staging[i];
        int r = atomicAdd(&hist[p >> 17], 1);
        sorted_src[lo + r] = p & 0x1FFFF;
    }
}

// ---------------- GAT aggregate ----------------
__global__ __launch_bounds__(256) void k_gat_agg(const uint32* __restrict__ hb32,
                                                 const float* __restrict__ a_src,
                                                 const float* __restrict__ a_dst,
                                                 const int* __restrict__ row_ptr,
                                                 const int* __restrict__ sorted_src,
                                                 uint32* __restrict__ out1b) {
    __shared__ int sbuf[4][64];
    __shared__ float wbuf[4][64][4];
    int lane = threadIdx.x & 63, wv = threadIdx.x >> 6;
    int node = blockIdx.x * 4 + wv;
    int start = row_ptr[node];
    int deg = row_ptr[node + 1] - start;
    if (deg == 0) {
        out1b[(size_t)node * 64 + lane] = 0u;
        return;
    }
    int head = lane >> 4;
    float4 ad = *(const float4*)&a_dst[node * 4];
    float4 den4 = make_float4(0.f, 0.f, 0.f, 0.f);
    float ac0[4] = {0.f, 0.f, 0.f, 0.f};
    float ac1[4] = {0.f, 0.f, 0.f, 0.f};
    for (int j0 = 0; j0 < deg; j0 += 64) {
        int j = j0 + lane;
        int s = 0;
        float4 w = make_float4(0.f, 0.f, 0.f, 0.f);
        if (j < deg) {
            s = sorted_src[start + j];
            float4 as = *(const float4*)&a_src[s * 4];
            w.x = __expf(lrelu(as.x + ad.x));
            w.y = __expf(lrelu(as.y + ad.y));
            w.z = __expf(lrelu(as.z + ad.z));
            w.w = __expf(lrelu(as.w + ad.w));
        }
        den4.x += w.x; den4.y += w.y; den4.z += w.z; den4.w += w.w;
        sbuf[wv][lane] = s;
        *(float4*)&wbuf[wv][lane][0] = w;
        __builtin_amdgcn_wave_barrier();
        int nj = min(64, deg - j0);
        int njf = nj & ~7;
        for (int jj = 0; jj < njf; jj += 8) {
#pragma unroll
            for (int u = 0; u < 8; ++u) {
                int ss = sbuf[wv][jj + u];
                float wh = wbuf[wv][jj + u][head];
                uint32 hv = hb32[((uint32)ss << 6) + lane];
                ac0[u & 3] = fmaf(wh, bflo(hv), ac0[u & 3]);
                ac1[u & 3] = fmaf(wh, bfhi(hv), ac1[u & 3]);
            }
        }
        for (int jj = njf; jj < nj; ++jj) {
            int ss = sbuf[wv][jj];
            float wh = wbuf[wv][jj][head];
            uint32 hv = hb32[((uint32)ss << 6) + lane];
            ac0[0] = fmaf(wh, bflo(hv), ac0[0]);
            ac1[0] = fmaf(wh, bfhi(hv), ac1[0]);
        }
        __builtin_amdgcn_wave_barrier();
    }
    // den = wave-sum of each lane's own staged w (padded lanes contributed 0)
#pragma unroll
    for (int m = 1; m < 64; m <<= 1) {
        den4.x += __shfl_xor(den4.x, m);
        den4.y += __shfl_xor(den4.y, m);
        den4.z += __shfl_xor(den4.z, m);
        den4.w += __shfl_xor(den4.w, m);
    }
    float den = head == 0 ? den4.x : head == 1 ? den4.y : head == 2 ? den4.z : den4.w;
    float rden = 1.f / den;
    float acc0 = (ac0[0] + ac0[1]) + (ac0[2] + ac0[3]);
    float acc1 = (ac1[0] + ac1[1]) + (ac1[2] + ac1[3]);
    out1b[(size_t)node * 64 + lane] = packbf(acc0 * rden, acc1 * rden);
}

// ---------------- GIN aggregate ----------------
__global__ __launch_bounds__(256) void k_gin_agg(const uint32* __restrict__ ob32,
                                                 const int* __restrict__ row_ptr,
                                                 const int* __restrict__ sorted_src,
                                                 const float* __restrict__ eps_ptr,
                                                 uint32* __restrict__ zb32) {
    __shared__ int sbuf[4][64];
    int lane = threadIdx.x & 63, wv = threadIdx.x >> 6;
    int node = blockIdx.x * 4 + wv;
    int start = row_ptr[node];
    int deg = row_ptr[node + 1] - start;
    float ac0[4] = {0.f, 0.f, 0.f, 0.f};
    float ac1[4] = {0.f, 0.f, 0.f, 0.f};
    for (int j0 = 0; j0 < deg; j0 += 64) {
        int j = j0 + lane;
        sbuf[wv][lane] = (j < deg) ? sorted_src[start + j] : 0;
        __builtin_amdgcn_wave_barrier();
        int nj = min(64, deg - j0);
        int njf = nj & ~7;
        for (int jj = 0; jj < njf; jj += 8) {
#pragma unroll
            for (int u = 0; u < 8; ++u) {
                int ss = sbuf[wv][jj + u];
                uint32 hv = ob32[((uint32)ss << 6) + lane];
                ac0[u & 3] += bflo(hv);
                ac1[u & 3] += bfhi(hv);
            }
        }
        for (int jj = njf; jj < nj; ++jj) {
            int ss = sbuf[wv][jj];
            uint32 hv = ob32[((uint32)ss << 6) + lane];
            ac0[0] += bflo(hv);
            ac1[0] += bfhi(hv);
        }
        __builtin_amdgcn_wave_barrier();
    }
    float ep = 1.f + eps_ptr[0];
    uint32 own = ob32[((uint32)node << 6) + lane];
    float z0 = fmaf(ep, bflo(own), (ac0[0] + ac0[1]) + (ac0[2] + ac0[3]));
    float z1 = fmaf(ep, bfhi(own), (ac1[0] + ac1[1]) + (ac1[2] + ac1[3]));
    zb32[(size_t)node * 64 + lane] = packbf(z0, z1);
}

// ---------------- BN stats (bf16 input) ----------------
__global__ __launch_bounds__(256) void k_bnstats_bf16(const uint32* __restrict__ buf,
                                                      float* __restrict__ acc) {
    __shared__ float sh[4][64][4];
    int lane = threadIdx.x & 63, grp = threadIdx.x >> 6;
    float s0 = 0.f, s1 = 0.f, q0 = 0.f, q1 = 0.f;
    for (int r = blockIdx.x * 4 + grp; r < N_NODES; r += gridDim.x * 4) {
        uint32 v = buf[(size_t)r * 64 + lane];
        float v0 = bflo(v), v1 = bfhi(v);
        s0 += v0; s1 += v1; q0 += v0 * v0; q1 += v1 * v1;
    }
    sh[grp][lane][0] = s0; sh[grp][lane][1] = s1;
    sh[grp][lane][2] = q0; sh[grp][lane][3] = q1;
    __syncthreads();
    if (grp == 0) {
#pragma unroll
        for (int g = 1; g < 4; ++g) {
            s0 += sh[g][lane][0]; s1 += sh[g][lane][1];
            q0 += sh[g][lane][2]; q1 += sh[g][lane][3];
        }
        int c0 = lane * 2;
        atomicAdd(&acc[c0], s0);
        atomicAdd(&acc[c0 + 1], s1);
        atomicAdd(&acc[128 + c0], q0);
        atomicAdd(&acc[128 + c0 + 1], q1);
    }
}

// ---------------- BN + ELU in-place on bf16 (params computed per-block) ----------------
__global__ __launch_bounds__(256) void k_bn_elu_b16(uint32* __restrict__ buf,
                                                    const float* __restrict__ acc,
                                                    const float* __restrict__ gamma,
                                                    const float* __restrict__ beta) {
    __shared__ float psc[128], psh[128];
    int t = threadIdx.x;
    if (t < 128) {
        float mu = acc[t] * (1.f / N_NODES);
        float var = acc[128 + t] * (1.f / N_NODES) - mu * mu;
        float s = rsqrtf(var + BN_EPS) * gamma[t];
        psc[t] = s;
        psh[t] = beta[t] - mu * s;
    }
    __syncthreads();
    size_t i = (size_t)blockIdx.x * 256 + t;
    if (i >= (size_t)N_NODES * 64) return;
    int c0 = (int)(i & 63) * 2;
    uint32 v = buf[i];
    float r0 = fmaf(bflo(v), psc[c0], psh[c0]);
    float r1 = fmaf(bfhi(v), psc[c0 + 1], psh[c0 + 1]);
    r0 = r0 > 0.f ? r0 : __expf(r0) - 1.f;
    r1 = r1 > 0.f ? r1 : __expf(r1) - 1.f;
    buf[i] = packbf(r0, r1);
}

// ---------------- BN + ELU: bf16 in -> fp32 out (final, params per-block) ----------------
__global__ __launch_bounds__(256) void k_bn_elu_out(const uint32* __restrict__ in,
                                                    const float* __restrict__ acc,
                                                    const float* __restrict__ gamma,
                                                    const float* __restrict__ beta,
                                                    float2* __restrict__ out) {
    __shared__ float psc[128], psh[128];
    int t = threadIdx.x;
    if (t < 128) {
        float mu = acc[t] * (1.f / N_NODES);
        float var = acc[128 + t] * (1.f / N_NODES) - mu * mu;
        float s = rsqrtf(var + BN_EPS) * gamma[t];
        psc[t] = s;
        psh[t] = beta[t] - mu * s;
    }
    __syncthreads();
    size_t i = (size_t)blockIdx.x * 256 + t;
    if (i >= (size_t)N_NODES * 64) return;
    int c0 = (int)(i & 63) * 2;
    uint32 v = in[i];
    float r0 = fmaf(bflo(v), psc[c0], psh[c0]);
    float r1 = fmaf(bfhi(v), psc[c0 + 1], psh[c0 + 1]);
    r0 = r0 > 0.f ? r0 : __expf(r0) - 1.f;
    r1 = r1 > 0.f ? r1 : __expf(r1) - 1.f;
    out[i] = make_float2(r0, r1);
}

extern "C" void kernel_launch(void* const* d_in, const int* in_sizes, int n_in,
                              void* d_out, int out_size, void* d_ws, size_t ws_size,
                              hipStream_t stream) {
    (void)in_sizes; (void)n_in; (void)out_size; (void)ws_size;
    const float* x       = (const float*)d_in[0];
    const float* W_gat   = (const float*)d_in[1];
    const float* att_src = (const float*)d_in[2];
    const float* att_dst = (const float*)d_in[3];
    // bias_gat / lin_b cancel exactly under batch-norm -> dropped
    const float* bn1_g   = (const float*)d_in[5];
    const float* bn1_b   = (const float*)d_in[6];
    const float* eps_gin = (const float*)d_in[7];
    const float* lin_W   = (const float*)d_in[8];
    const float* bn2_g   = (const float*)d_in[10];
    const float* bn2_b   = (const float*)d_in[11];
    const int*   ei      = (const int*)d_in[12];
    float* out = (float*)d_out;

    char* w = (char*)d_ws;
    size_t o = 0;
    auto take = [&](size_t b) -> char* {
        char* p = w + o;
        o += (b + 255) & ~(size_t)255;
        return p;
    };
    unsigned short* hb   = (unsigned short*)take((size_t)N_NODES * 128 * 2);
    unsigned short* Wt1  = (unsigned short*)take((size_t)128 * IN_C * 2);
    unsigned short* Wt2  = (unsigned short*)take((size_t)128 * HID * 2);
    uint32* o1b          = (uint32*)take((size_t)N_NODES * 64 * 4);
    float* a_src         = (float*)take((size_t)N_NODES * 4 * 4);
    float* a_dst         = (float*)take((size_t)N_NODES * 4 * 4);
    int*   sorted        = (int*)take((size_t)N_EDGES * 4);
    int*   staging       = (int*)take((size_t)N_EDGES * 4);
    int*   row_ptr       = (int*)take((size_t)(N_NODES + 1) * 4);
    int*   bcount        = (int*)take((NBUCK + 1) * 4);
    int*   bucket_base   = (int*)take((NBUCK + 1) * 4);
    int*   gcursor       = (int*)take((NBUCK + 1) * 4);
    float* bnacc         = (float*)take(512 * 4);
    uint32* zb  = (uint32*)hb;  // reuse: hb dead after k_gat_agg
    uint32* o2b = o1b;          // reuse: o1b dead after k_gin_agg

    const int nGemmBlocks = (N_NODES + 127) / 128;
    const int nElemBlocks = (N_NODES * 64 + 255) / 256;

    k_init<<<1, 512, 0, stream>>>(bcount, bnacc);
    k_transpose_all<<<((IN_C + HID) * 128 + 255) / 256, 256, 0, stream>>>(W_gat, lin_W,
                                                                          Wt1, Wt2);
    k_gemm<true, false><<<nGemmBlocks, 256, 0, stream>>>(x, Wt1, hb, IN_C);
    k_att<<<N_NODES / 2, 256, 0, stream>>>(hb, att_src, att_dst, a_src, a_dst);
    k_bucket_count<<<256, 256, 0, stream>>>(ei, bcount);
    k_bucket_scan<<<1, 512, 0, stream>>>(bcount, bucket_base, gcursor, row_ptr);
    k_partition<<<NPART, 256, 0, stream>>>(ei, gcursor, staging);
    k_bucket_sort<<<NBUCK, 256, 0, stream>>>(staging, bucket_base, row_ptr, sorted);
    k_gat_agg<<<N_NODES / 4, 256, 0, stream>>>((const uint32*)hb, a_src, a_dst, row_ptr,
                                               sorted, o1b);
    k_bnstats_bf16<<<512, 256, 0, stream>>>(o1b, bnacc);
    k_bn_elu_b16<<<nElemBlocks, 256, 0, stream>>>(o1b, bnacc, bn1_g, bn1_b);
    k_gin_agg<<<N_NODES / 4, 256, 0, stream>>>(o1b, row_ptr, sorted, eps_gin, zb);
    k_gemm<false, false><<<nGemmBlocks, 256, 0, stream>>>(zb, Wt2, o2b, HID);
    k_bnstats_bf16<<<512, 256, 0, stream>>>(o2b, bnacc + 256);
    k_bn_elu_out<<<nElemBlocks, 256, 0, stream>>>(o2b, bnacc + 256, bn2_g, bn2_b,
                                                  (float2*)out);
}

// Round 7
// 541.448 us; speedup vs baseline: 1.0120x; 1.0120x over previous
//
#include <hip/hip_runtime.h>

#define N_NODES 100000
#define N_EDGES 1600000
#define IN_C 256
#define HID 128
#define NEG_SLOPE 0.2f
#define BN_EPS 1e-5f
#define NBUCK 391          // ceil(N_NODES/256): bucket b covers dst [b*256,(b+1)*256)
#define NPART 391          // ceil(N_EDGES/4096) partition tiles

typedef unsigned int uint32;
typedef __attribute__((ext_vector_type(8))) short bf16x8;
typedef __attribute__((ext_vector_type(4))) float f32x4;

__device__ __forceinline__ float lrelu(float x) { return x > 0.f ? x : NEG_SLOPE * x; }

__device__ __forceinline__ unsigned short f2bf(float f) {
    uint32 u = __float_as_uint(f);
    u += 0x7fffu + ((u >> 16) & 1u);
    return (unsigned short)(u >> 16);
}
__device__ __forceinline__ float bf2f(unsigned short h) {
    return __uint_as_float(((uint32)h) << 16);
}
__device__ __forceinline__ float bflo(uint32 v) { return __uint_as_float(v << 16); }
__device__ __forceinline__ float bfhi(uint32 v) { return __uint_as_float(v & 0xffff0000u); }
__device__ __forceinline__ uint32 packbf(float a, float b) {
    return (uint32)f2bf(a) | ((uint32)f2bf(b) << 16);
}

// ---------------- init ----------------
__global__ void k_init(int* __restrict__ bcount, float* __restrict__ bnacc) {
    int t = threadIdx.x;
    if (t < NBUCK) bcount[t] = 0;
    if (t < 512) bnacc[t] = 0.f;
}

// ---------------- transpose both W: [K][128] fp32 -> [128][K] bf16 ----------------
__global__ void k_transpose_all(const float* __restrict__ W1, const float* __restrict__ W2,
                                unsigned short* __restrict__ Wt1,
                                unsigned short* __restrict__ Wt2) {
    int idx = blockIdx.x * 256 + threadIdx.x;
    if (idx < IN_C * 128) {
        int k = idx >> 7, n = idx & 127;
        Wt1[n * IN_C + k] = f2bf(W1[idx]);
    } else {
        idx -= IN_C * 128;
        if (idx < HID * 128) {
            int k = idx >> 7, n = idx & 127;
            Wt2[n * HID + k] = f2bf(W2[idx]);
        }
    }
}

// ---------------- MFMA GEMM, register-prefetch pipelined ----------------
template <bool AF32, bool OUTF32>
__global__ __launch_bounds__(256) void k_gemm(const void* __restrict__ Av,
                                              const unsigned short* __restrict__ Wt,
                                              void* __restrict__ Out, int K) {
    __shared__ unsigned short As[128 * 72];
    __shared__ unsigned short Bs[128 * 72];
    const int t = threadIdx.x;
    const int n0 = blockIdx.x * 128;
    const int wv = t >> 6, lane = t & 63;
    const int wy = wv >> 1, wx = wv & 1;
    const int lm = lane & 15, lg = lane >> 4;
    const float* Af = (const float*)Av;
    const unsigned short* Ah = (const unsigned short*)Av;

    f32x4 acc[4][4];
#pragma unroll
    for (int i = 0; i < 4; ++i)
#pragma unroll
        for (int j = 0; j < 4; ++j) acc[i][j] = (f32x4){0.f, 0.f, 0.f, 0.f};

    float4 afp[8];
    uint4 ahp[4];
    uint4 bvp[4];

    if (AF32) {
#pragma unroll
        for (int p = 0; p < 8; ++p) {
            int idx = p * 256 + t, row = idx >> 4, c4 = idx & 15, gn = n0 + row;
            afp[p] = (gn < N_NODES) ? *(const float4*)&Af[(size_t)gn * K + c4 * 4]
                                    : make_float4(0.f, 0.f, 0.f, 0.f);
        }
    } else {
#pragma unroll
        for (int p = 0; p < 4; ++p) {
            int idx = p * 256 + t, row = idx >> 3, c = idx & 7, gn = n0 + row;
            ahp[p] = (gn < N_NODES) ? *(const uint4*)&Ah[(size_t)gn * K + c * 8]
                                    : make_uint4(0, 0, 0, 0);
        }
    }
#pragma unroll
    for (int p = 0; p < 4; ++p) {
        int idx = p * 256 + t, n = idx >> 3, c = idx & 7;
        bvp[p] = *(const uint4*)&Wt[(size_t)n * K + c * 8];
    }

    for (int kc = 0; kc < K; kc += 64) {
        if (AF32) {
#pragma unroll
            for (int p = 0; p < 8; ++p) {
                int idx = p * 256 + t, row = idx >> 4, c4 = idx & 15;
                ushort4 b;
                b.x = f2bf(afp[p].x); b.y = f2bf(afp[p].y);
                b.z = f2bf(afp[p].z); b.w = f2bf(afp[p].w);
                *(ushort4*)&As[row * 72 + c4 * 4] = b;
            }
        } else {
#pragma unroll
            for (int p = 0; p < 4; ++p) {
                int idx = p * 256 + t, row = idx >> 3, c = idx & 7;
                *(uint4*)&As[row * 72 + c * 8] = ahp[p];
            }
        }
#pragma unroll
        for (int p = 0; p < 4; ++p) {
            int idx = p * 256 + t, n = idx >> 3, c = idx & 7;
            *(uint4*)&Bs[n * 72 + c * 8] = bvp[p];
        }
        __syncthreads();
        int kn = kc + 64;
        if (kn < K) {
            if (AF32) {
#pragma unroll
                for (int p = 0; p < 8; ++p) {
                    int idx = p * 256 + t, row = idx >> 4, c4 = idx & 15, gn = n0 + row;
                    afp[p] = (gn < N_NODES) ? *(const float4*)&Af[(size_t)gn * K + kn + c4 * 4]
                                            : make_float4(0.f, 0.f, 0.f, 0.f);
                }
            } else {
#pragma unroll
                for (int p = 0; p < 4; ++p) {
                    int idx = p * 256 + t, row = idx >> 3, c = idx & 7, gn = n0 + row;
                    ahp[p] = (gn < N_NODES) ? *(const uint4*)&Ah[(size_t)gn * K + kn + c * 8]
                                            : make_uint4(0, 0, 0, 0);
                }
            }
#pragma unroll
            for (int p = 0; p < 4; ++p) {
                int idx = p * 256 + t, n = idx >> 3, c = idx & 7;
                bvp[p] = *(const uint4*)&Wt[(size_t)n * K + kn + c * 8];
            }
        }
#pragma unroll
        for (int ks = 0; ks < 2; ++ks) {
            bf16x8 af[4], bfr[4];
#pragma unroll
            for (int i = 0; i < 4; ++i)
                af[i] = *(const bf16x8*)&As[(wy * 64 + i * 16 + lm) * 72 + ks * 32 + lg * 8];
#pragma unroll
            for (int j = 0; j < 4; ++j)
                bfr[j] = *(const bf16x8*)&Bs[(wx * 64 + j * 16 + lm) * 72 + ks * 32 + lg * 8];
#pragma unroll
            for (int i = 0; i < 4; ++i)
#pragma unroll
                for (int j = 0; j < 4; ++j)
                    acc[i][j] = __builtin_amdgcn_mfma_f32_16x16x32_bf16(af[i], bfr[j],
                                                                        acc[i][j], 0, 0, 0);
        }
        __syncthreads();
    }
#pragma unroll
    for (int i = 0; i < 4; ++i) {
#pragma unroll
        for (int r = 0; r < 4; ++r) {
            int row = n0 + wy * 64 + i * 16 + lg * 4 + r;
            if (row < N_NODES) {
#pragma unroll
                for (int j = 0; j < 4; ++j) {
                    int col = wx * 64 + j * 16 + lm;
                    float v = acc[i][j][r];
                    if (OUTF32) ((float*)Out)[(size_t)row * 128 + col] = v;
                    else ((unsigned short*)Out)[(size_t)row * 128 + col] = f2bf(v);
                }
            }
        }
    }
}

// ---------------- attention coefficients ----------------
__global__ __launch_bounds__(256) void k_att(const unsigned short* __restrict__ hb,
                                             const float* __restrict__ att_s,
                                             const float* __restrict__ att_d,
                                             float* __restrict__ a_src,
                                             float* __restrict__ a_dst) {
    int node = blockIdx.x * 2 + (threadIdx.x >> 7);
    int c = threadIdx.x & 127;
    float hv = bf2f(hb[(size_t)node * 128 + c]);
    float ps = hv * att_s[c];
    float pd = hv * att_d[c];
#pragma unroll
    for (int m = 1; m < 32; m <<= 1) {
        ps += __shfl_xor(ps, m);
        pd += __shfl_xor(pd, m);
    }
    if ((c & 31) == 0) {
        int head = c >> 5;
        a_src[node * 4 + head] = ps;
        a_dst[node * 4 + head] = pd;
    }
}

// ---------------- CSR build: two-phase bucket sort ----------------
__global__ __launch_bounds__(256) void k_bucket_count(const int* __restrict__ ei,
                                                      int* __restrict__ bcount) {
    __shared__ int hist[NBUCK];
    for (int i = threadIdx.x; i < NBUCK; i += 256) hist[i] = 0;
    __syncthreads();
    for (int e = blockIdx.x * 256 + threadIdx.x; e < N_EDGES; e += gridDim.x * 256)
        atomicAdd(&hist[ei[N_EDGES + e] >> 8], 1);
    __syncthreads();
    for (int i = threadIdx.x; i < NBUCK; i += 256)
        if (hist[i]) atomicAdd(&bcount[i], hist[i]);
}

__global__ void k_bucket_scan(const int* __restrict__ bcount, int* __restrict__ bucket_base,
                              int* __restrict__ gcursor, int* __restrict__ row_ptr) {
    __shared__ int sh[512];
    int t = threadIdx.x;
    int v0 = (t < NBUCK) ? bcount[t] : 0;
    int val = v0;
    sh[t] = val;
    __syncthreads();
    for (int off = 1; off < 512; off <<= 1) {
        int o = (t >= off) ? sh[t - off] : 0;
        __syncthreads();
        val += o;
        sh[t] = val;
        __syncthreads();
    }
    if (t < NBUCK) {
        int e = val - v0;
        bucket_base[t] = e;
        gcursor[t] = e;
    }
    if (t == 0) {
        bucket_base[NBUCK] = N_EDGES;
        row_ptr[N_NODES] = N_EDGES;
    }
}

__global__ __launch_bounds__(256) void k_partition(const int* __restrict__ ei,
                                                   int* __restrict__ gcursor,
                                                   int* __restrict__ staging) {
    __shared__ int hist[NBUCK];
    __shared__ int base[NBUCK];
    int t = threadIdx.x;
    int e0 = blockIdx.x * 4096;
    for (int i = t; i < NBUCK; i += 256) hist[i] = 0;
    __syncthreads();
    int pk[16], cb[16];
#pragma unroll
    for (int u = 0; u < 16; ++u) {
        int e = e0 + u * 256 + t;
        cb[u] = -1;
        if (e < N_EDGES) {
            int s = ei[e], d = ei[N_EDGES + e];
            int b = d >> 8;
            int r = atomicAdd(&hist[b], 1);
            pk[u] = ((d & 255) << 17) | s;
            cb[u] = (r << 9) | b;
        }
    }
    __syncthreads();
    for (int i = t; i < NBUCK; i += 256)
        if (hist[i]) base[i] = atomicAdd(&gcursor[i], hist[i]);
    __syncthreads();
#pragma unroll
    for (int u = 0; u < 16; ++u) {
        if (cb[u] >= 0) {
            int b = cb[u] & 511, r = cb[u] >> 9;
            staging[base[b] + r] = pk[u];
        }
    }
}

__global__ __launch_bounds__(256) void k_bucket_sort(const int* __restrict__ staging,
                                                     const int* __restrict__ bucket_base,
                                                     int* __restrict__ row_ptr,
                                                     int* __restrict__ sorted_src) {
    __shared__ int hist[256];
    __shared__ int sh[256];
    int t = threadIdx.x, b = blockIdx.x;
    int lo = bucket_base[b], hi = bucket_base[b + 1];
    hist[t] = 0;
    __syncthreads();
    for (int i = lo + t; i < hi; i += 256) atomicAdd(&hist[staging[i] >> 17], 1);
    __syncthreads();
    int v0 = hist[t];
    int val = v0;
    sh[t] = val;
    __syncthreads();
    for (int off = 1; off < 256; off <<= 1) {
        int o = (t >= off) ? sh[t - off] : 0;
        __syncthreads();
        val += o;
        sh[t] = val;
        __syncthreads();
    }
    int excl = val - v0;
    int d = b * 256 + t;
    if (d < N_NODES) row_ptr[d] = lo + excl;
    hist[t] = excl;
    __syncthreads();
    for (int i = lo + t; i < hi; i += 256) {
        int p = staging[i];
        int r = atomicAdd(&hist[p >> 17], 1);
        sorted_src[lo + r] = p & 0x1FFFF;
    }
}

// ---------------- GAT aggregate: 4 edges per wave-load (dwordx4) ----------------
// sub=lane>>4 picks edge, chl=lane&15 picks 16B (8 ch) of the 256B row.
// One global_load_dwordx4 = 1KB/wave = 4 edges. Channel partials folded by
// shfl_xor(16,32) at the end. Padded lanes stage w=0 -> zero-weight FMAs safe.
__global__ __launch_bounds__(256) void k_gat_agg(const uint4* __restrict__ h4,
                                                 const float* __restrict__ a_src,
                                                 const float* __restrict__ a_dst,
                                                 const int* __restrict__ row_ptr,
                                                 const int* __restrict__ sorted_src,
                                                 uint4* __restrict__ out1b4) {
    __shared__ int sbuf[4][64];
    __shared__ float wbuf[4][64][4];
    int lane = threadIdx.x & 63, wv = threadIdx.x >> 6;
    int sub = lane >> 4, chl = lane & 15, hd = chl >> 2;
    int node = blockIdx.x * 4 + wv;
    int start = row_ptr[node];
    int deg = row_ptr[node + 1] - start;
    if (deg == 0) {
        if (lane < 16) out1b4[((uint32)node << 4) + chl] = make_uint4(0u, 0u, 0u, 0u);
        return;
    }
    float4 ad = *(const float4*)&a_dst[node * 4];
    float4 den4 = make_float4(0.f, 0.f, 0.f, 0.f);
    float acc[8] = {0.f, 0.f, 0.f, 0.f, 0.f, 0.f, 0.f, 0.f};
    for (int j0 = 0; j0 < deg; j0 += 64) {
        int j = j0 + lane;
        int s = 0;
        float4 w = make_float4(0.f, 0.f, 0.f, 0.f);
        if (j < deg) {
            s = sorted_src[start + j];
            float4 as = *(const float4*)&a_src[s * 4];
            w.x = __expf(lrelu(as.x + ad.x));
            w.y = __expf(lrelu(as.y + ad.y));
            w.z = __expf(lrelu(as.z + ad.z));
            w.w = __expf(lrelu(as.w + ad.w));
        }
        den4.x += w.x; den4.y += w.y; den4.z += w.z; den4.w += w.w;
        sbuf[wv][lane] = s;
        *(float4*)&wbuf[wv][lane][0] = w;
        __builtin_amdgcn_wave_barrier();
        int nj16 = (min(64, deg - j0) + 15) & ~15;
        for (int jj = 0; jj < nj16; jj += 16) {
#pragma unroll
            for (int u = 0; u < 4; ++u) {
                int e = jj + u * 4 + sub;
                int ss = sbuf[wv][e];
                float wh = wbuf[wv][e][hd];
                uint4 hv = h4[((uint32)ss << 4) + chl];
                acc[0] += wh * bflo(hv.x); acc[1] += wh * bfhi(hv.x);
                acc[2] += wh * bflo(hv.y); acc[3] += wh * bfhi(hv.y);
                acc[4] += wh * bflo(hv.z); acc[5] += wh * bfhi(hv.z);
                acc[6] += wh * bflo(hv.w); acc[7] += wh * bfhi(hv.w);
            }
        }
        __builtin_amdgcn_wave_barrier();
    }
    // fold edge-subgroups: lanes {chl, chl+16, chl+32, chl+48} hold same channels
#pragma unroll
    for (int m = 16; m < 64; m <<= 1)
#pragma unroll
        for (int c = 0; c < 8; ++c) acc[c] += __shfl_xor(acc[c], m);
    // den = wave-sum of each lane's staged w
#pragma unroll
    for (int m = 1; m < 64; m <<= 1) {
        den4.x += __shfl_xor(den4.x, m);
        den4.y += __shfl_xor(den4.y, m);
        den4.z += __shfl_xor(den4.z, m);
        den4.w += __shfl_xor(den4.w, m);
    }
    float den = hd == 0 ? den4.x : hd == 1 ? den4.y : hd == 2 ? den4.z : den4.w;
    float rden = 1.f / den;
    if (lane < 16) {
        uint4 o;
        o.x = packbf(acc[0] * rden, acc[1] * rden);
        o.y = packbf(acc[2] * rden, acc[3] * rden);
        o.z = packbf(acc[4] * rden, acc[5] * rden);
        o.w = packbf(acc[6] * rden, acc[7] * rden);
        out1b4[((uint32)node << 4) + chl] = o;
    }
}

// ---------------- GIN aggregate: same 4-edges-per-load layout ----------------
__global__ __launch_bounds__(256) void k_gin_agg(const uint4* __restrict__ ob4,
                                                 const int* __restrict__ row_ptr,
                                                 const int* __restrict__ sorted_src,
                                                 const float* __restrict__ eps_ptr,
                                                 uint4* __restrict__ zb4) {
    __shared__ int sbuf[4][64];
    __shared__ float mbuf[4][64];
    int lane = threadIdx.x & 63, wv = threadIdx.x >> 6;
    int sub = lane >> 4, chl = lane & 15;
    int node = blockIdx.x * 4 + wv;
    int start = row_ptr[node];
    int deg = row_ptr[node + 1] - start;
    float acc[8] = {0.f, 0.f, 0.f, 0.f, 0.f, 0.f, 0.f, 0.f};
    for (int j0 = 0; j0 < deg; j0 += 64) {
        int j = j0 + lane;
        int s = 0;
        float m = 0.f;
        if (j < deg) { s = sorted_src[start + j]; m = 1.f; }
        sbuf[wv][lane] = s;
        mbuf[wv][lane] = m;
        __builtin_amdgcn_wave_barrier();
        int nj16 = (min(64, deg - j0) + 15) & ~15;
        for (int jj = 0; jj < nj16; jj += 16) {
#pragma unroll
            for (int u = 0; u < 4; ++u) {
                int e = jj + u * 4 + sub;
                int ss = sbuf[wv][e];
                float mm = mbuf[wv][e];
                uint4 hv = ob4[((uint32)ss << 4) + chl];
                acc[0] += mm * bflo(hv.x); acc[1] += mm * bfhi(hv.x);
                acc[2] += mm * bflo(hv.y); acc[3] += mm * bfhi(hv.y);
                acc[4] += mm * bflo(hv.z); acc[5] += mm * bfhi(hv.z);
                acc[6] += mm * bflo(hv.w); acc[7] += mm * bfhi(hv.w);
            }
        }
        __builtin_amdgcn_wave_barrier();
    }
#pragma unroll
    for (int m = 16; m < 64; m <<= 1)
#pragma unroll
        for (int c = 0; c < 8; ++c) acc[c] += __shfl_xor(acc[c], m);
    if (lane < 16) {
        float ep = 1.f + eps_ptr[0];
        uint4 own = ob4[((uint32)node << 4) + chl];
        uint4 o;
        o.x = packbf(fmaf(ep, bflo(own.x), acc[0]), fmaf(ep, bfhi(own.x), acc[1]));
        o.y = packbf(fmaf(ep, bflo(own.y), acc[2]), fmaf(ep, bfhi(own.y), acc[3]));
        o.z = packbf(fmaf(ep, bflo(own.z), acc[4]), fmaf(ep, bfhi(own.z), acc[5]));
        o.w = packbf(fmaf(ep, bflo(own.w), acc[6]), fmaf(ep, bfhi(own.w), acc[7]));
        zb4[((uint32)node << 4) + chl] = o;
    }
}

// ---------------- BN stats (bf16 input) ----------------
__global__ __launch_bounds__(256) void k_bnstats_bf16(const uint32* __restrict__ buf,
                                                      float* __restrict__ acc) {
    __shared__ float sh[4][64][4];
    int lane = threadIdx.x & 63, grp = threadIdx.x >> 6;
    float s0 = 0.f, s1 = 0.f, q0 = 0.f, q1 = 0.f;
    for (int r = blockIdx.x * 4 + grp; r < N_NODES; r += gridDim.x * 4) {
        uint32 v = buf[(size_t)r * 64 + lane];
        float v0 = bflo(v), v1 = bfhi(v);
        s0 += v0; s1 += v1; q0 += v0 * v0; q1 += v1 * v1;
    }
    sh[grp][lane][0] = s0; sh[grp][lane][1] = s1;
    sh[grp][lane][2] = q0; sh[grp][lane][3] = q1;
    __syncthreads();
    if (grp == 0) {
#pragma unroll
        for (int g = 1; g < 4; ++g) {
            s0 += sh[g][lane][0]; s1 += sh[g][lane][1];
            q0 += sh[g][lane][2]; q1 += sh[g][lane][3];
        }
        int c0 = lane * 2;
        atomicAdd(&acc[c0], s0);
        atomicAdd(&acc[c0 + 1], s1);
        atomicAdd(&acc[128 + c0], q0);
        atomicAdd(&acc[128 + c0 + 1], q1);
    }
}

// ---------------- BN + ELU in-place on bf16 (params computed per-block) ----------------
__global__ __launch_bounds__(256) void k_bn_elu_b16(uint32* __restrict__ buf,
                                                    const float* __restrict__ acc,
                                                    const float* __restrict__ gamma,
                                                    const float* __restrict__ beta) {
    __shared__ float psc[128], psh[128];
    int t = threadIdx.x;
    if (t < 128) {
        float mu = acc[t] * (1.f / N_NODES);
        float var = acc[128 + t] * (1.f / N_NODES) - mu * mu;
        float s = rsqrtf(var + BN_EPS) * gamma[t];
        psc[t] = s;
        psh[t] = beta[t] - mu * s;
    }
    __syncthreads();
    size_t i = (size_t)blockIdx.x * 256 + t;
    if (i >= (size_t)N_NODES * 64) return;
    int c0 = (int)(i & 63) * 2;
    uint32 v = buf[i];
    float r0 = fmaf(bflo(v), psc[c0], psh[c0]);
    float r1 = fmaf(bfhi(v), psc[c0 + 1], psh[c0 + 1]);
    r0 = r0 > 0.f ? r0 : __expf(r0) - 1.f;
    r1 = r1 > 0.f ? r1 : __expf(r1) - 1.f;
    buf[i] = packbf(r0, r1);
}

// ---------------- BN + ELU: bf16 in -> fp32 out (final, params per-block) ----------------
__global__ __launch_bounds__(256) void k_bn_elu_out(const uint32* __restrict__ in,
                                                    const float* __restrict__ acc,
                                                    const float* __restrict__ gamma,
                                                    const float* __restrict__ beta,
                                                    float2* __restrict__ out) {
    __shared__ float psc[128], psh[128];
    int t = threadIdx.x;
    if (t < 128) {
        float mu = acc[t] * (1.f / N_NODES);
        float var = acc[128 + t] * (1.f / N_NODES) - mu * mu;
        float s = rsqrtf(var + BN_EPS) * gamma[t];
        psc[t] = s;
        psh[t] = beta[t] - mu * s;
    }
    __syncthreads();
    size_t i = (size_t)blockIdx.x * 256 + t;
    if (i >= (size_t)N_NODES * 64) return;
    int c0 = (int)(i & 63) * 2;
    uint32 v = in[i];
    float r0 = fmaf(bflo(v), psc[c0], psh[c0]);
    float r1 = fmaf(bfhi(v), psc[c0 + 1], psh[c0 + 1]);
    r0 = r0 > 0.f ? r0 : __expf(r0) - 1.f;
    r1 = r1 > 0.f ? r1 : __expf(r1) - 1.f;
    out[i] = make_float2(r0, r1);
}

extern "C" void kernel_launch(void* const* d_in, const int* in_sizes, int n_in,
                              void* d_out, int out_size, void* d_ws, size_t ws_size,
                              hipStream_t stream) {
    (void)in_sizes; (void)n_in; (void)out_size; (void)ws_size;
    const float* x       = (const float*)d_in[0];
    const float* W_gat   = (const float*)d_in[1];
    const float* att_src = (const float*)d_in[2];
    const float* att_dst = (const float*)d_in[3];
    // bias_gat / lin_b cancel exactly under batch-norm -> dropped
    const float* bn1_g   = (const float*)d_in[5];
    const float* bn1_b   = (const float*)d_in[6];
    const float* eps_gin = (const float*)d_in[7];
    const float* lin_W   = (const float*)d_in[8];
    const float* bn2_g   = (const float*)d_in[10];
    const float* bn2_b   = (const float*)d_in[11];
    const int*   ei      = (const int*)d_in[12];
    float* out = (float*)d_out;

    char* w = (char*)d_ws;
    size_t o = 0;
    auto take = [&](size_t b) -> char* {
        char* p = w + o;
        o += (b + 255) & ~(size_t)255;
        return p;
    };
    unsigned short* hb   = (unsigned short*)take((size_t)N_NODES * 128 * 2);
    unsigned short* Wt1  = (unsigned short*)take((size_t)128 * IN_C * 2);
    unsigned short* Wt2  = (unsigned short*)take((size_t)128 * HID * 2);
    uint32* o1b          = (uint32*)take((size_t)N_NODES * 64 * 4);
    float* a_src         = (float*)take((size_t)N_NODES * 4 * 4);
    float* a_dst         = (float*)take((size_t)N_NODES * 4 * 4);
    int*   sorted        = (int*)take((size_t)N_EDGES * 4);
    int*   staging       = (int*)take((size_t)N_EDGES * 4);
    int*   row_ptr       = (int*)take((size_t)(N_NODES + 1) * 4);
    int*   bcount        = (int*)take((NBUCK + 1) * 4);
    int*   bucket_base   = (int*)take((NBUCK + 1) * 4);
    int*   gcursor       = (int*)take((NBUCK + 1) * 4);
    float* bnacc         = (float*)take(512 * 4);
    uint32* zb  = (uint32*)hb;  // reuse: hb dead after k_gat_agg
    uint32* o2b = o1b;          // reuse: o1b dead after k_gin_agg

    const int nGemmBlocks = (N_NODES + 127) / 128;
    const int nElemBlocks = (N_NODES * 64 + 255) / 256;

    k_init<<<1, 512, 0, stream>>>(bcount, bnacc);
    k_transpose_all<<<((IN_C + HID) * 128 + 255) / 256, 256, 0, stream>>>(W_gat, lin_W,
                                                                          Wt1, Wt2);
    k_gemm<true, false><<<nGemmBlocks, 256, 0, stream>>>(x, Wt1, hb, IN_C);
    k_att<<<N_NODES / 2, 256, 0, stream>>>(hb, att_src, att_dst, a_src, a_dst);
    k_bucket_count<<<256, 256, 0, stream>>>(ei, bcount);
    k_bucket_scan<<<1, 512, 0, stream>>>(bcount, bucket_base, gcursor, row_ptr);
    k_partition<<<NPART, 256, 0, stream>>>(ei, gcursor, staging);
    k_bucket_sort<<<NBUCK, 256, 0, stream>>>(staging, bucket_base, row_ptr, sorted);
    k_gat_agg<<<N_NODES / 4, 256, 0, stream>>>((const uint4*)hb, a_src, a_dst, row_ptr,
                                               sorted, (uint4*)o1b);
    k_bnstats_bf16<<<512, 256, 0, stream>>>(o1b, bnacc);
    k_bn_elu_b16<<<nElemBlocks, 256, 0, stream>>>(o1b, bnacc, bn1_g, bn1_b);
    k_gin_agg<<<N_NODES / 4, 256, 0, stream>>>((const uint4*)o1b, row_ptr, sorted,
                                               eps_gin, (uint4*)zb);
    k_gemm<false, false><<<nGemmBlocks, 256, 0, stream>>>(zb, Wt2, o2b, HID);
    k_bnstats_bf16<<<512, 256, 0, stream>>>(o2b, bnacc + 256);
    k_bn_elu_out<<<nElemBlocks, 256, 0, stream>>>(o2b, bnacc + 256, bn2_g, bn2_b,
                                                  (float2*)out);
}